// Round 3
// baseline (1543.058 us; speedup 1.0000x reference)
//
#include <hip/hip_runtime.h>
#include <hip/hip_bf16.h>

#define S3 3
#define BB 8
#define TT 48
#define NN 207
#define FF 256        // D_MODEL
#define DI 512        // D_INNER
#define DSN 16        // D_STATE
#define RR 16         // DT_RANK
#define LL 12
#define BN (BB*NN)    // 1656
#define XZS 516       // sXZ padded row stride (516 % 32 = 4 -> conflict-free)

__device__ __forceinline__ float fma4(float4 w, float4 v, float acc) {
    acc = fmaf(w.x, v.x, acc);
    acc = fmaf(w.y, v.y, acc);
    acc = fmaf(w.z, v.z, acc);
    acc = fmaf(w.w, v.w, acc);
    return acc;
}

// ---------------------------------------------------------------------------
// K1: per (scale, bn) sequence: in_proj -> conv+silu -> x_proj -> (dt_proj +
// scan fused) -> y   (y includes *silu(z_last) and D*xc_last)
// LDS 71,872 B -> 2 blocks/CU. All LDS accesses stride-1-across-lanes or
// broadcast -> no bank conflicts.
// ---------------------------------------------------------------------------
__global__ __launch_bounds__(256, 2)
void k1_seq(const float* __restrict__ x,
            const float* __restrict__ in_proj_w,
            const float* __restrict__ conv_w,
            const float* __restrict__ conv_b,
            const float* __restrict__ x_proj_w,
            const float* __restrict__ dt_proj_w,
            const float* __restrict__ dt_proj_b,
            const float* __restrict__ A_log,
            const float* __restrict__ Dw,
            float* __restrict__ ws_y)
{
    const int bn   = blockIdx.x;
    const int s    = blockIdx.y;
    const int tid  = threadIdx.x;
    const int lane = tid & 63;
    const int wv   = tid >> 6;
    const int b    = bn / NN;
    const int n    = bn % NN;

    __shared__ float sXZ[LL * XZS];     // 6192 f: xr then xc (stride 516)
    __shared__ float sWU[8192];         // A: W^T tile [32][256]; C: [48][68]; E: [16][260]
    __shared__ float sXA[LL * FF];      // A: x_seq [12][256]; C+: x_dbl [12][48]
    __shared__ float sZ[DI];            // z at l=11

    // ---- load x_seq (gather the scale's 12 time steps) ----
    const int t0 = (s == 0) ? 36 : (s == 1) ? 24 : 0;
    const int st = (s == 0) ? 1  : (s == 1) ? 2  : 4;
    for (int i = tid; i < LL * FF / 4; i += 256) {   // 768 float4
        int l  = i >> 6;
        int k4 = (i & 63) << 2;
        float4 v = *(const float4*)(x + (((size_t)b * TT + (t0 + l * st)) * NN + n) * FF + k4);
        *(float4*)&sXA[l * FF + k4] = v;
    }

    // ---- phase A (xr half): xz[l][e] for e in [0,512), all 12 l ----
    // W-tile transposed in LDS: [32 k][256 e]; thread owns e = e0 + tid.
    for (int et = 0; et < 2; ++et) {
        const int e0 = et << 8;
        float acc[12];
        #pragma unroll
        for (int l = 0; l < 12; ++l) acc[l] = 0.f;

        for (int k0 = 0; k0 < 256; k0 += 32) {
            __syncthreads();
            // stage: thread t loads W[e0+t][k0..k0+31] (128B contiguous), writes transposed
            const float* wg = in_proj_w + ((size_t)s * 1024 + e0 + tid) * 256 + k0;
            float4 wq[8];
            #pragma unroll
            for (int c = 0; c < 8; ++c) wq[c] = *(const float4*)(wg + (c << 2));
            #pragma unroll
            for (int c = 0; c < 8; ++c) {
                sWU[((c << 2) + 0) * 256 + tid] = wq[c].x;   // stride-1 across lanes
                sWU[((c << 2) + 1) * 256 + tid] = wq[c].y;
                sWU[((c << 2) + 2) * 256 + tid] = wq[c].z;
                sWU[((c << 2) + 3) * 256 + tid] = wq[c].w;
            }
            __syncthreads();

            float w[32];
            #pragma unroll
            for (int k = 0; k < 32; ++k) w[k] = sWU[k * 256 + tid];  // conflict-free

            #pragma unroll
            for (int l = 0; l < 12; ++l) {
                const float* xr = &sXA[l * FF + k0];
                #pragma unroll
                for (int c = 0; c < 8; ++c) {
                    float4 xq = *(const float4*)(xr + (c << 2));     // broadcast
                    acc[l] = fmaf(w[(c << 2) + 0], xq.x, acc[l]);
                    acc[l] = fmaf(w[(c << 2) + 1], xq.y, acc[l]);
                    acc[l] = fmaf(w[(c << 2) + 2], xq.z, acc[l]);
                    acc[l] = fmaf(w[(c << 2) + 3], xq.w, acc[l]);
                }
            }
        }
        #pragma unroll
        for (int l = 0; l < 12; ++l)
            sXZ[l * XZS + e0 + tid] = acc[l];                        // stride-1
    }

    // ---- z (e in [512,1024), only l=11): direct from global, coalesced rows ----
    {
        float4 x11 = *(const float4*)&sXA[11 * FF + (lane << 2)];    // conflict-free
        const float* wz = in_proj_w + ((size_t)s * 1024 + 512 + (wv << 7)) * 256;
        for (int r = 0; r < 128; ++r) {
            float4 wq = *(const float4*)(wz + (size_t)r * 256 + (lane << 2)); // 1KB/row coalesced
            float p = fma4(wq, x11, 0.f);
            #pragma unroll
            for (int off = 32; off; off >>= 1) p += __shfl_xor(p, off);
            if (lane == 0) sZ[(wv << 7) + r] = p;
        }
    }
    __syncthreads();

    // ---- phase B: causal conv4 + silu, in place per column ----
    for (int d = tid; d < DI; d += 256) {
        float4 cw = *(const float4*)(conv_w + ((size_t)s * DI + d) * 4);
        float  cb = conv_b[s * DI + d];
        float r[LL];
        #pragma unroll
        for (int l = 0; l < LL; ++l) r[l] = sXZ[l * XZS + d];
        #pragma unroll
        for (int l = 0; l < LL; ++l) {
            float v = cb;
            if (l >= 3) v = fmaf(r[l - 3], cw.x, v);
            if (l >= 2) v = fmaf(r[l - 2], cw.y, v);
            if (l >= 1) v = fmaf(r[l - 1], cw.z, v);
            v = fmaf(r[l], cw.w, v);
            v = v / (1.0f + __expf(-v));        // silu
            sXZ[l * XZS + d] = v;
        }
    }

    // ---- phase C: x_dbl = xc @ x_proj_w^T  (12 x 48, K=512, k-tile 64) ----
    const int cl = tid >> 4;      // 0..15 (valid < 12)
    const int og = tid & 15;      // 16 groups of 3 outputs
    float c0 = 0.f, c1 = 0.f, c2 = 0.f;
    for (int k0 = 0; k0 < 512; k0 += 64) {
        __syncthreads();
        // stage x_proj_w[0..47][k0..k0+63], stride 68
        #pragma unroll
        for (int j = 0; j < 3; ++j) {
            int idx = tid + (j << 8);           // float4 idx 0..767
            int row = idx >> 4;                 // 16 float4 per row
            int k4  = (idx & 15) << 2;
            float4 w = *(const float4*)(x_proj_w + ((size_t)s * 48 + row) * 512 + k0 + k4);
            *(float4*)&sWU[row * 68 + k4] = w;
        }
        __syncthreads();
        if (cl < 12) {
            for (int k = 0; k < 64; k += 4) {
                float4 xv = *(const float4*)&sXZ[cl * XZS + k0 + k];  // 4 addrs, disjoint banks
                float4 wa = *(const float4*)&sWU[(og * 3 + 0) * 68 + k];
                float4 wb = *(const float4*)&sWU[(og * 3 + 1) * 68 + k];
                float4 wc = *(const float4*)&sWU[(og * 3 + 2) * 68 + k];
                c0 = fma4(wa, xv, c0);
                c1 = fma4(wb, xv, c1);
                c2 = fma4(wc, xv, c2);
            }
        }
    }
    __syncthreads();   // sWU compute done; sXA (x_seq) dead -> reuse as x_dbl
    if (cl < 12) {
        sXA[cl * 48 + og * 3 + 0] = c0;
        sXA[cl * 48 + og * 3 + 1] = c1;
        sXA[cl * 48 + og * 3 + 2] = c2;
    }

    // ---- phase E: dt_proj + softplus + scan + y, d in two halves of 256 ----
    for (int dh = 0; dh < 2; ++dh) {
        __syncthreads();
        // stage dt_proj_w[s][dh*256 + dl][r] transposed -> sWU[r*260 + dl]
        #pragma unroll
        for (int j = 0; j < 4; ++j) {
            int idx = tid + (j << 8);           // 0..1023
            int dl  = idx >> 2;                 // 0..255
            int c   = idx & 3;
            float4 w = *(const float4*)(dt_proj_w + ((size_t)s * DI + dh * 256 + dl) * RR + (c << 2));
            sWU[((c << 2) + 0) * 260 + dl] = w.x;
            sWU[((c << 2) + 1) * 260 + dl] = w.y;
            sWU[((c << 2) + 2) * 260 + dl] = w.z;
            sWU[((c << 2) + 3) * 260 + dl] = w.w;
        }
        __syncthreads();

        const int d = dh * 256 + tid;
        float dpb = dt_proj_b[s * DI + d];
        float wr[16];
        #pragma unroll
        for (int r = 0; r < 16; ++r) wr[r] = sWU[r * 260 + tid];     // stride-1

        float a[16];
        #pragma unroll
        for (int c = 0; c < 16; c += 4) {
            float4 al = *(const float4*)(A_log + ((size_t)s * DI + d) * 16 + c);
            a[c + 0] = -__expf(al.x);
            a[c + 1] = -__expf(al.y);
            a[c + 2] = -__expf(al.z);
            a[c + 3] = -__expf(al.w);
        }

        float h[16];
        #pragma unroll
        for (int n2 = 0; n2 < 16; ++n2) h[n2] = 0.0f;
        float xc_last = 0.0f;

        #pragma unroll
        for (int l = 0; l < LL; ++l) {
            float v = dpb;
            #pragma unroll
            for (int r = 0; r < 16; ++r) v = fmaf(sXA[l * 48 + r], wr[r], v);
            float e = __expf(-fabsf(v));
            float dtl = fmaxf(v, 0.0f) + __logf(1.0f + e);   // softplus

            float xcv = sXZ[l * XZS + d];
            float dx  = dtl * xcv;
            #pragma unroll
            for (int n2 = 0; n2 < 16; ++n2) {
                float Bn = sXA[l * 48 + 16 + n2];
                h[n2] = fmaf(__expf(dtl * a[n2]), h[n2], dx * Bn);
            }
            xc_last = xcv;
        }

        float y = 0.0f;
        #pragma unroll
        for (int n2 = 0; n2 < 16; ++n2) y = fmaf(h[n2], sXA[11 * 48 + 32 + n2], y);
        y = fmaf(Dw[s * DI + d], xc_last, y);
        float zv = sZ[d];
        y *= zv / (1.0f + __expf(-zv));         // * silu(z_last)
        ws_y[((size_t)(s * BN + bn)) * DI + d] = y;
    }
}

// ---------------------------------------------------------------------------
// K_WT: transpose out_proj_w [3][256][512] -> wT [3][512][256]
// ---------------------------------------------------------------------------
__global__ __launch_bounds__(256)
void k_wt(const float* __restrict__ w, float* __restrict__ wT)
{
    int idx = blockIdx.x * 256 + threadIdx.x;   // over 3*512*256, e fastest
    int e = idx & 255;
    int k = (idx >> 8) & 511;
    int s = idx >> 17;
    wT[idx] = w[((size_t)s * 256 + e) * 512 + k];
}

// ---------------------------------------------------------------------------
// K2: per bn: feats[s][e] = y[s] . wT[s][:,e]; then attn softmax blend -> out
// ---------------------------------------------------------------------------
__global__ __launch_bounds__(256)
void k2_fused(const float* __restrict__ ws_y,
              const float* __restrict__ wT,
              const float* __restrict__ attn_w,
              const float* __restrict__ attn_b,
              float* __restrict__ out)
{
    const int bn  = blockIdx.x;
    const int tid = threadIdx.x;

    __shared__ float sy[3 * DI];        // 6 KB
    __shared__ float sP[4][3 * 256];    // per-wave partials, 12 KB
    __shared__ float red[3][4];

    for (int i = tid; i < 384; i += 256) {          // 3*512/4 float4
        int ss = i >> 7;
        int k4 = (i & 127) << 2;
        *(float4*)&sy[ss * DI + k4] =
            *(const float4*)&ws_y[((size_t)ss * BN + bn) * DI + k4];
    }
    __syncthreads();

    const int kk = tid >> 6;            // wave id 0..3 = k-slice
    const int eq = (tid & 63) << 2;     // e base (float4 along e)

    #pragma unroll
    for (int ss = 0; ss < 3; ++ss) {
        float4 acc = make_float4(0.f, 0.f, 0.f, 0.f);
        for (int k = kk; k < DI; k += 4) {
            float  yv = sy[ss * DI + k];                          // wave-uniform broadcast
            float4 w  = *(const float4*)&wT[((size_t)ss * DI + k) * 256 + eq];
            acc.x = fmaf(w.x, yv, acc.x);
            acc.y = fmaf(w.y, yv, acc.y);
            acc.z = fmaf(w.z, yv, acc.z);
            acc.w = fmaf(w.w, yv, acc.w);
        }
        *(float4*)&sP[kk][ss * 256 + eq] = acc;
    }
    __syncthreads();

    // thread owns e = tid
    float f0 = sP[0][0*256+tid] + sP[1][0*256+tid] + sP[2][0*256+tid] + sP[3][0*256+tid];
    float f1 = sP[0][1*256+tid] + sP[1][1*256+tid] + sP[2][1*256+tid] + sP[3][1*256+tid];
    float f2 = sP[0][2*256+tid] + sP[1][2*256+tid] + sP[2][2*256+tid] + sP[3][2*256+tid];

    float aw = attn_w[tid];
    float p0 = f0 * aw, p1 = f1 * aw, p2 = f2 * aw;
    #pragma unroll
    for (int off = 32; off > 0; off >>= 1) {
        p0 += __shfl_down(p0, off);
        p1 += __shfl_down(p1, off);
        p2 += __shfl_down(p2, off);
    }
    int wvv = tid >> 6, ln = tid & 63;
    if (ln == 0) { red[0][wvv] = p0; red[1][wvv] = p1; red[2][wvv] = p2; }
    __syncthreads();

    float ab = attn_b[0];
    float s0 = red[0][0] + red[0][1] + red[0][2] + red[0][3] + ab;
    float s1 = red[1][0] + red[1][1] + red[1][2] + red[1][3] + ab;
    float s2 = red[2][0] + red[2][1] + red[2][2] + red[2][3] + ab;
    float m  = fmaxf(s0, fmaxf(s1, s2));
    float e0 = __expf(s0 - m), e1 = __expf(s1 - m), e2 = __expf(s2 - m);
    float inv = 1.0f / (e0 + e1 + e2);
    out[(size_t)bn * 256 + tid] = (e0 * f0 + e1 * f1 + e2 * f2) * inv;
}

extern "C" void kernel_launch(void* const* d_in, const int* in_sizes, int n_in,
                              void* d_out, int out_size, void* d_ws, size_t ws_size,
                              hipStream_t stream) {
    const float* x         = (const float*)d_in[0];
    const float* in_proj_w = (const float*)d_in[1];
    const float* conv_w    = (const float*)d_in[2];
    const float* conv_b    = (const float*)d_in[3];
    const float* x_proj_w  = (const float*)d_in[4];
    const float* dt_proj_w = (const float*)d_in[5];
    const float* dt_proj_b = (const float*)d_in[6];
    const float* A_log     = (const float*)d_in[7];
    const float* Dw        = (const float*)d_in[8];
    const float* out_proj_w= (const float*)d_in[9];
    const float* attn_w    = (const float*)d_in[10];
    const float* attn_b    = (const float*)d_in[11];
    float* outp = (float*)d_out;

    float* ws_y = (float*)d_ws;                         // 3*1656*512 f32 = 10.2 MB
    float* wT   = ws_y + (size_t)S3 * BN * DI;          // 3*512*256 f32 = 1.5 MB

    hipLaunchKernelGGL(k_wt, dim3((S3 * 512 * 256) / 256), dim3(256), 0, stream,
                       out_proj_w, wT);
    hipLaunchKernelGGL(k1_seq, dim3(BN, S3), dim3(256), 0, stream,
                       x, in_proj_w, conv_w, conv_b, x_proj_w,
                       dt_proj_w, dt_proj_b, A_log, Dw, ws_y);
    hipLaunchKernelGGL(k2_fused, dim3(BN), dim3(256), 0, stream,
                       ws_y, wT, attn_w, attn_b, outp);
}

// Round 4
// 667.575 us; speedup vs baseline: 2.3114x; 2.3114x over previous
//
#include <hip/hip_runtime.h>
#include <hip/hip_bf16.h>

#define S3 3
#define BB 8
#define TT 48
#define NN 207
#define FF 256        // D_MODEL
#define DI 512        // D_INNER
#define DSN 16        // D_STATE
#define RR 16         // DT_RANK
#define LL 12
#define BN (BB*NN)    // 1656
#define MROWS (BN*LL) // 19872
#define XZS 516       // padded row stride (516 % 32 = 4 -> conflict-free)

__device__ __forceinline__ float fma4(float4 w, float4 v, float acc) {
    acc = fmaf(w.x, v.x, acc);
    acc = fmaf(w.y, v.y, acc);
    acc = fmaf(w.z, v.z, acc);
    acc = fmaf(w.w, v.w, acc);
    return acc;
}

// x row base for gathered row m = bn*12 + l (scale params t0, st)
__device__ __forceinline__ size_t xrow_base(int m, int t0, int st) {
    int bn = m / 12, l = m - bn * 12;
    int b  = bn / NN, n = bn - b * NN;
    return (((size_t)b * TT + t0 + l * st) * NN + n) * FF;
}

// ---------------------------------------------------------------------------
// K_GEMM_IN: xz_r[m][n] = sum_k x_gather[m][k] * W[s][n][k]
//   M = 19872 (bn*12+l, gather fused), N = 512 (xr half), K = 256
//   BM=128, BN=128, BK=16; 256 thr; 8x8 reg tile -> FMA-bound
// ---------------------------------------------------------------------------
__global__ __launch_bounds__(256, 4)
void k_gemm_in(const float* __restrict__ x,
               const float* __restrict__ in_proj_w,
               float* __restrict__ cout, int s, int t0, int st)
{
    const int tid = threadIdx.x;
    const int m0  = blockIdx.x * 128;
    const int n0  = blockIdx.y * 128;

    __shared__ float sA[16][128];   // 8 KB, k-major
    __shared__ float sB[16][128];   // 8 KB, k-major

    const int tx = tid & 15;        // n-group
    const int ty = tid >> 4;        // m-group

    float acc[8][8];
    #pragma unroll
    for (int i = 0; i < 8; ++i)
        #pragma unroll
        for (int j = 0; j < 8; ++j) acc[i][j] = 0.f;

    // staging: thread handles rows rA0=tid>>2 and rA0+64, k-quad kq
    const int r0 = tid >> 2;
    const int r1 = r0 + 64;
    const int kq = (tid & 3) << 2;

    const int mA0 = m0 + r0, mA1 = m0 + r1;
    const float* pA0 = x + xrow_base(mA0 < MROWS ? mA0 : 0, t0, st) + kq;
    const float* pA1 = x + xrow_base(mA1 < MROWS ? mA1 : 0, t0, st) + kq;
    const float* pB0 = in_proj_w + ((size_t)s * 1024 + n0 + r0) * 256 + kq;
    const float* pB1 = in_proj_w + ((size_t)s * 1024 + n0 + r1) * 256 + kq;

    for (int k0 = 0; k0 < 256; k0 += 16) {
        __syncthreads();
        float4 a0 = *(const float4*)(pA0 + k0);
        float4 a1 = *(const float4*)(pA1 + k0);
        float4 b0 = *(const float4*)(pB0 + k0);
        float4 b1 = *(const float4*)(pB1 + k0);
        sA[kq + 0][r0] = a0.x; sA[kq + 1][r0] = a0.y;
        sA[kq + 2][r0] = a0.z; sA[kq + 3][r0] = a0.w;
        sA[kq + 0][r1] = a1.x; sA[kq + 1][r1] = a1.y;
        sA[kq + 2][r1] = a1.z; sA[kq + 3][r1] = a1.w;
        sB[kq + 0][r0] = b0.x; sB[kq + 1][r0] = b0.y;
        sB[kq + 2][r0] = b0.z; sB[kq + 3][r0] = b0.w;
        sB[kq + 0][r1] = b1.x; sB[kq + 1][r1] = b1.y;
        sB[kq + 2][r1] = b1.z; sB[kq + 3][r1] = b1.w;
        __syncthreads();

        #pragma unroll
        for (int k = 0; k < 16; ++k) {
            float aF[8], bF[8];
            *(float4*)&aF[0] = *(const float4*)&sA[k][ty * 8];     // broadcast x16
            *(float4*)&aF[4] = *(const float4*)&sA[k][ty * 8 + 4];
            *(float4*)&bF[0] = *(const float4*)&sB[k][tx * 8];
            *(float4*)&bF[4] = *(const float4*)&sB[k][tx * 8 + 4];
            #pragma unroll
            for (int i = 0; i < 8; ++i)
                #pragma unroll
                for (int j = 0; j < 8; ++j)
                    acc[i][j] = fmaf(aF[i], bF[j], acc[i][j]);
        }
    }

    #pragma unroll
    for (int i = 0; i < 8; ++i) {
        int m = m0 + ty * 8 + i;
        if (m < MROWS) {
            float4 v0 = make_float4(acc[i][0], acc[i][1], acc[i][2], acc[i][3]);
            float4 v1 = make_float4(acc[i][4], acc[i][5], acc[i][6], acc[i][7]);
            *(float4*)&cout[(size_t)m * 512 + n0 + tx * 8]     = v0;
            *(float4*)&cout[(size_t)m * 512 + n0 + tx * 8 + 4] = v1;
        }
    }
}

// ---------------------------------------------------------------------------
// K1Z: z[s][bn][e] = x[b, t_last, n, :] . W[s][512+e][:]   (l=11 rows only)
//   grid (13, 4, 3); same tile structure as k_gemm_in
// ---------------------------------------------------------------------------
__global__ __launch_bounds__(256, 4)
void k1z(const float* __restrict__ x,
         const float* __restrict__ in_proj_w,
         float* __restrict__ ws_z)
{
    const int tid = threadIdx.x;
    const int m0  = blockIdx.x * 128;
    const int n0  = blockIdx.y * 128;
    const int s   = blockIdx.z;
    const int tl  = (s == 0) ? 47 : (s == 1) ? 46 : 44;   // t0 + 11*st

    __shared__ float sA[16][128];
    __shared__ float sB[16][128];

    const int tx = tid & 15;
    const int ty = tid >> 4;

    float acc[8][8];
    #pragma unroll
    for (int i = 0; i < 8; ++i)
        #pragma unroll
        for (int j = 0; j < 8; ++j) acc[i][j] = 0.f;

    const int r0 = tid >> 2;
    const int r1 = r0 + 64;
    const int kq = (tid & 3) << 2;

    int bn0c = m0 + r0; if (bn0c >= BN) bn0c = 0;
    int bn1c = m0 + r1; if (bn1c >= BN) bn1c = 0;
    int b0i = bn0c / NN, n0i = bn0c - b0i * NN;
    int b1i = bn1c / NN, n1i = bn1c - b1i * NN;
    const float* pA0 = x + (((size_t)b0i * TT + tl) * NN + n0i) * FF + kq;
    const float* pA1 = x + (((size_t)b1i * TT + tl) * NN + n1i) * FF + kq;
    const float* pB0 = in_proj_w + ((size_t)s * 1024 + 512 + n0 + r0) * 256 + kq;
    const float* pB1 = in_proj_w + ((size_t)s * 1024 + 512 + n0 + r1) * 256 + kq;

    for (int k0 = 0; k0 < 256; k0 += 16) {
        __syncthreads();
        float4 a0 = *(const float4*)(pA0 + k0);
        float4 a1 = *(const float4*)(pA1 + k0);
        float4 b0 = *(const float4*)(pB0 + k0);
        float4 b1 = *(const float4*)(pB1 + k0);
        sA[kq + 0][r0] = a0.x; sA[kq + 1][r0] = a0.y;
        sA[kq + 2][r0] = a0.z; sA[kq + 3][r0] = a0.w;
        sA[kq + 0][r1] = a1.x; sA[kq + 1][r1] = a1.y;
        sA[kq + 2][r1] = a1.z; sA[kq + 3][r1] = a1.w;
        sB[kq + 0][r0] = b0.x; sB[kq + 1][r0] = b0.y;
        sB[kq + 2][r0] = b0.z; sB[kq + 3][r0] = b0.w;
        sB[kq + 0][r1] = b1.x; sB[kq + 1][r1] = b1.y;
        sB[kq + 2][r1] = b1.z; sB[kq + 3][r1] = b1.w;
        __syncthreads();

        #pragma unroll
        for (int k = 0; k < 16; ++k) {
            float aF[8], bF[8];
            *(float4*)&aF[0] = *(const float4*)&sA[k][ty * 8];
            *(float4*)&aF[4] = *(const float4*)&sA[k][ty * 8 + 4];
            *(float4*)&bF[0] = *(const float4*)&sB[k][tx * 8];
            *(float4*)&bF[4] = *(const float4*)&sB[k][tx * 8 + 4];
            #pragma unroll
            for (int i = 0; i < 8; ++i)
                #pragma unroll
                for (int j = 0; j < 8; ++j)
                    acc[i][j] = fmaf(aF[i], bF[j], acc[i][j]);
        }
    }

    #pragma unroll
    for (int i = 0; i < 8; ++i) {
        int bn = m0 + ty * 8 + i;
        if (bn < BN) {
            float4 v0 = make_float4(acc[i][0], acc[i][1], acc[i][2], acc[i][3]);
            float4 v1 = make_float4(acc[i][4], acc[i][5], acc[i][6], acc[i][7]);
            *(float4*)&ws_z[((size_t)s * BN + bn) * 512 + n0 + tx * 8]     = v0;
            *(float4*)&ws_z[((size_t)s * BN + bn) * 512 + n0 + tx * 8 + 4] = v1;
        }
    }
}

// ---------------------------------------------------------------------------
// K_SCAN: per bn (for scale s): conv+silu -> x_proj -> dt_proj+scan -> y
//   reads xz rows from ws_xz, z from ws_z. LDS 43.7 KB -> 3 blocks/CU.
// ---------------------------------------------------------------------------
__global__ __launch_bounds__(256, 3)
void k_scan(const float* __restrict__ ws_xz,
            const float* __restrict__ ws_z,
            const float* __restrict__ conv_w,
            const float* __restrict__ conv_b,
            const float* __restrict__ x_proj_w,
            const float* __restrict__ dt_proj_w,
            const float* __restrict__ dt_proj_b,
            const float* __restrict__ A_log,
            const float* __restrict__ Dw,
            float* __restrict__ ws_y, int s)
{
    const int bn  = blockIdx.x;
    const int tid = threadIdx.x;

    __shared__ float sXC[LL * XZS];     // 6192 f
    __shared__ float sWU[4160];         // C: [48][68]; E: [16][260]
    __shared__ float sDBL[LL * 48];     // x_dbl

    // ---- load xz rows (contiguous 24 KB) ----
    const float* src = ws_xz + (size_t)bn * LL * 512;
    for (int i = tid; i < LL * 128; i += 256) {     // 1536 float4
        int l  = i >> 7;
        int k4 = (i & 127) << 2;
        *(float4*)&sXC[l * XZS + k4] = *(const float4*)(src + l * 512 + k4);
    }
    __syncthreads();

    // ---- conv4 + silu in place ----
    for (int d = tid; d < DI; d += 256) {
        float4 cw = *(const float4*)(conv_w + ((size_t)s * DI + d) * 4);
        float  cb = conv_b[s * DI + d];
        float r[LL];
        #pragma unroll
        for (int l = 0; l < LL; ++l) r[l] = sXC[l * XZS + d];
        #pragma unroll
        for (int l = 0; l < LL; ++l) {
            float v = cb;
            if (l >= 3) v = fmaf(r[l - 3], cw.x, v);
            if (l >= 2) v = fmaf(r[l - 2], cw.y, v);
            if (l >= 1) v = fmaf(r[l - 1], cw.z, v);
            v = fmaf(r[l], cw.w, v);
            v = v / (1.0f + __expf(-v));
            sXC[l * XZS + d] = v;
        }
    }

    // ---- x_dbl = xc @ x_proj_w^T  (12 x 48, K=512, k-tile 64) ----
    const int cl = tid >> 4;
    const int og = tid & 15;
    float c0 = 0.f, c1 = 0.f, c2 = 0.f;
    for (int k0 = 0; k0 < 512; k0 += 64) {
        __syncthreads();
        #pragma unroll
        for (int j = 0; j < 3; ++j) {
            int idx = tid + (j << 8);
            int row = idx >> 4;
            int k4  = (idx & 15) << 2;
            float4 w = *(const float4*)(x_proj_w + ((size_t)s * 48 + row) * 512 + k0 + k4);
            *(float4*)&sWU[row * 68 + k4] = w;
        }
        __syncthreads();
        if (cl < 12) {
            for (int k = 0; k < 64; k += 4) {
                float4 xv = *(const float4*)&sXC[cl * XZS + k0 + k];
                float4 wa = *(const float4*)&sWU[(og * 3 + 0) * 68 + k];
                float4 wb = *(const float4*)&sWU[(og * 3 + 1) * 68 + k];
                float4 wc = *(const float4*)&sWU[(og * 3 + 2) * 68 + k];
                c0 = fma4(wa, xv, c0);
                c1 = fma4(wb, xv, c1);
                c2 = fma4(wc, xv, c2);
            }
        }
    }
    __syncthreads();
    if (cl < 12) {
        sDBL[cl * 48 + og * 3 + 0] = c0;
        sDBL[cl * 48 + og * 3 + 1] = c1;
        sDBL[cl * 48 + og * 3 + 2] = c2;
    }

    // ---- dt_proj + softplus + scan + y, d in two halves ----
    for (int dh = 0; dh < 2; ++dh) {
        __syncthreads();
        #pragma unroll
        for (int j = 0; j < 4; ++j) {
            int idx = tid + (j << 8);
            int dl  = idx >> 2;
            int c   = idx & 3;
            float4 w = *(const float4*)(dt_proj_w + ((size_t)s * DI + dh * 256 + dl) * RR + (c << 2));
            sWU[((c << 2) + 0) * 260 + dl] = w.x;
            sWU[((c << 2) + 1) * 260 + dl] = w.y;
            sWU[((c << 2) + 2) * 260 + dl] = w.z;
            sWU[((c << 2) + 3) * 260 + dl] = w.w;
        }
        __syncthreads();

        const int d = dh * 256 + tid;
        float dpb = dt_proj_b[s * DI + d];
        float wr[16];
        #pragma unroll
        for (int r = 0; r < 16; ++r) wr[r] = sWU[r * 260 + tid];

        float a[16];
        #pragma unroll
        for (int c = 0; c < 16; c += 4) {
            float4 al = *(const float4*)(A_log + ((size_t)s * DI + d) * 16 + c);
            a[c + 0] = -__expf(al.x);
            a[c + 1] = -__expf(al.y);
            a[c + 2] = -__expf(al.z);
            a[c + 3] = -__expf(al.w);
        }

        float h[16];
        #pragma unroll
        for (int n2 = 0; n2 < 16; ++n2) h[n2] = 0.0f;
        float xc_last = 0.0f;

        #pragma unroll
        for (int l = 0; l < LL; ++l) {
            float v = dpb;
            #pragma unroll
            for (int r = 0; r < 16; ++r) v = fmaf(sDBL[l * 48 + r], wr[r], v);
            float e = __expf(-fabsf(v));
            float dtl = fmaxf(v, 0.0f) + __logf(1.0f + e);   // softplus

            float xcv = sXC[l * XZS + d];
            float dx  = dtl * xcv;
            #pragma unroll
            for (int n2 = 0; n2 < 16; ++n2) {
                float Bn = sDBL[l * 48 + 16 + n2];
                h[n2] = fmaf(__expf(dtl * a[n2]), h[n2], dx * Bn);
            }
            xc_last = xcv;
        }

        float y = 0.0f;
        #pragma unroll
        for (int n2 = 0; n2 < 16; ++n2) y = fmaf(h[n2], sDBL[11 * 48 + 32 + n2], y);
        y = fmaf(Dw[s * DI + d], xc_last, y);
        float zv = ws_z[((size_t)s * BN + bn) * 512 + d];
        y *= zv / (1.0f + __expf(-zv));
        ws_y[((size_t)(s * BN + bn)) * DI + d] = y;
    }
}

// ---------------------------------------------------------------------------
// K_WT: transpose out_proj_w [3][256][512] -> wT [3][512][256]
// ---------------------------------------------------------------------------
__global__ __launch_bounds__(256)
void k_wt(const float* __restrict__ w, float* __restrict__ wT)
{
    int idx = blockIdx.x * 256 + threadIdx.x;
    int e = idx & 255;
    int k = (idx >> 8) & 511;
    int s = idx >> 17;
    wT[idx] = w[((size_t)s * 256 + e) * 512 + k];
}

// ---------------------------------------------------------------------------
// K2: per bn: feats[s][e] = y[s] . wT[s][:,e]; attn softmax blend -> out
// ---------------------------------------------------------------------------
__global__ __launch_bounds__(256)
void k2_fused(const float* __restrict__ ws_y,
              const float* __restrict__ wT,
              const float* __restrict__ attn_w,
              const float* __restrict__ attn_b,
              float* __restrict__ out)
{
    const int bn  = blockIdx.x;
    const int tid = threadIdx.x;

    __shared__ float sy[3 * DI];
    __shared__ float sP[4][3 * 256];
    __shared__ float red[3][4];

    for (int i = tid; i < 384; i += 256) {
        int ss = i >> 7;
        int k4 = (i & 127) << 2;
        *(float4*)&sy[ss * DI + k4] =
            *(const float4*)&ws_y[((size_t)ss * BN + bn) * DI + k4];
    }
    __syncthreads();

    const int kk = tid >> 6;
    const int eq = (tid & 63) << 2;

    #pragma unroll
    for (int ss = 0; ss < 3; ++ss) {
        float4 acc = make_float4(0.f, 0.f, 0.f, 0.f);
        for (int k = kk; k < DI; k += 4) {
            float  yv = sy[ss * DI + k];
            float4 w  = *(const float4*)&wT[((size_t)ss * DI + k) * 256 + eq];
            acc.x = fmaf(w.x, yv, acc.x);
            acc.y = fmaf(w.y, yv, acc.y);
            acc.z = fmaf(w.z, yv, acc.z);
            acc.w = fmaf(w.w, yv, acc.w);
        }
        *(float4*)&sP[kk][ss * 256 + eq] = acc;
    }
    __syncthreads();

    float f0 = sP[0][0*256+tid] + sP[1][0*256+tid] + sP[2][0*256+tid] + sP[3][0*256+tid];
    float f1 = sP[0][1*256+tid] + sP[1][1*256+tid] + sP[2][1*256+tid] + sP[3][1*256+tid];
    float f2 = sP[0][2*256+tid] + sP[1][2*256+tid] + sP[2][2*256+tid] + sP[3][2*256+tid];

    float aw = attn_w[tid];
    float p0 = f0 * aw, p1 = f1 * aw, p2 = f2 * aw;
    #pragma unroll
    for (int off = 32; off > 0; off >>= 1) {
        p0 += __shfl_down(p0, off);
        p1 += __shfl_down(p1, off);
        p2 += __shfl_down(p2, off);
    }
    int wvv = tid >> 6, ln = tid & 63;
    if (ln == 0) { red[0][wvv] = p0; red[1][wvv] = p1; red[2][wvv] = p2; }
    __syncthreads();

    float ab = attn_b[0];
    float s0 = red[0][0] + red[0][1] + red[0][2] + red[0][3] + ab;
    float s1 = red[1][0] + red[1][1] + red[1][2] + red[1][3] + ab;
    float s2 = red[2][0] + red[2][1] + red[2][2] + red[2][3] + ab;
    float m  = fmaxf(s0, fmaxf(s1, s2));
    float e0 = __expf(s0 - m), e1 = __expf(s1 - m), e2 = __expf(s2 - m);
    float inv = 1.0f / (e0 + e1 + e2);
    out[(size_t)bn * 256 + tid] = (e0 * f0 + e1 * f1 + e2 * f2) * inv;
}

extern "C" void kernel_launch(void* const* d_in, const int* in_sizes, int n_in,
                              void* d_out, int out_size, void* d_ws, size_t ws_size,
                              hipStream_t stream) {
    const float* x         = (const float*)d_in[0];
    const float* in_proj_w = (const float*)d_in[1];
    const float* conv_w    = (const float*)d_in[2];
    const float* conv_b    = (const float*)d_in[3];
    const float* x_proj_w  = (const float*)d_in[4];
    const float* dt_proj_w = (const float*)d_in[5];
    const float* dt_proj_b = (const float*)d_in[6];
    const float* A_log     = (const float*)d_in[7];
    const float* Dw        = (const float*)d_in[8];
    const float* out_proj_w= (const float*)d_in[9];
    const float* attn_w    = (const float*)d_in[10];
    const float* attn_b    = (const float*)d_in[11];
    float* outp = (float*)d_out;

    // ws layout (floats):
    float* ws_xz = (float*)d_ws;                        // 19872*512   = 40.7 MB (reused per scale)
    float* ws_z  = ws_xz + (size_t)MROWS * 512;         // 3*1656*512  = 10.2 MB
    float* ws_y  = ws_z  + (size_t)S3 * BN * DI;        // 3*1656*512  = 10.2 MB
    float* wT    = ws_y  + (size_t)S3 * BN * DI;        // 3*512*256   = 1.5 MB

    const int t0s[3] = {36, 24, 0};
    const int sts[3] = {1, 2, 4};

    hipLaunchKernelGGL(k_wt, dim3((S3 * 512 * 256) / 256), dim3(256), 0, stream,
                       out_proj_w, wT);
    hipLaunchKernelGGL(k1z, dim3(13, 4, 3), dim3(256), 0, stream,
                       x, in_proj_w, ws_z);

    for (int s = 0; s < 3; ++s) {
        hipLaunchKernelGGL(k_gemm_in, dim3(156, 4), dim3(256), 0, stream,
                           x, in_proj_w, ws_xz, s, t0s[s], sts[s]);
        hipLaunchKernelGGL(k_scan, dim3(BN), dim3(256), 0, stream,
                           ws_xz, ws_z, conv_w, conv_b, x_proj_w,
                           dt_proj_w, dt_proj_b, A_log, Dw, ws_y, s);
    }

    hipLaunchKernelGGL(k2_fused, dim3(BN), dim3(256), 0, stream,
                       ws_y, wT, attn_w, attn_b, outp);
}